// Round 5
// baseline (645.506 us; speedup 1.0000x reference)
//
#include <hip/hip_runtime.h>
#include <hip/hip_bf16.h>

#define B_ 4
#define H_ 16
#define N_ 2048
#define D_ 64
#define BM 256   // q-rows per WG (64 per wave)
#define BN 64    // kv per iter

typedef __bf16 bf16;
typedef bf16 bf16x4 __attribute__((ext_vector_type(4)));
typedef bf16 bf16x8 __attribute__((ext_vector_type(8)));
typedef float f32x4 __attribute__((ext_vector_type(4)));

#define SCALE_LOG2E 0.18033688011112042f  // (1/sqrt(64)) * log2(e)

#define GBL(p) ((const __attribute__((address_space(1))) void*)(p))
#define LDS(p) ((__attribute__((address_space(3))) void*)(p))

// Build DMA-ready swizzled tile images in DRAM (512 blocks: tile x rep).
__global__ __launch_bounds__(256) void convert_kv(const float* __restrict__ k,
                                                  const float* __restrict__ v,
                                                  bf16* __restrict__ kbf_sw,
                                                  bf16* __restrict__ vtf_sw) {
    const int tile = blockIdx.x >> 1;
    const int rep  = blockIdx.x & 1;
    const int b = tile >> 5, T = tile & 31;
    const int t = threadIdx.x;

    const int p  = t + rep * 256;     // physical unit 0..511
    const int r  = p >> 3;            // row within tile
    const int up = p & 7;             // physical 16B unit
    const int u  = up ^ (r & 7);      // logical unit
    // K: row r = kv, unit u = d/8
    {
        const float* src = k + ((size_t)(b * N_ + T * 64 + r) * D_ + u * 8);
        float4 a = *(const float4*)src;
        float4 c = *(const float4*)(src + 4);
        bf16x8 o;
        o[0] = (bf16)a.x; o[1] = (bf16)a.y; o[2] = (bf16)a.z; o[3] = (bf16)a.w;
        o[4] = (bf16)c.x; o[5] = (bf16)c.y; o[6] = (bf16)c.z; o[7] = (bf16)c.w;
        *(bf16x8*)(kbf_sw + (size_t)tile * 4096 + p * 8) = o;
    }
    // V^T: row r = d, unit u = n_local/8 (transpose gathers, L1-amortized)
    {
        const float* src = v + ((size_t)(b * N_ + T * 64 + u * 8) * D_ + r);
        bf16x8 o;
        #pragma unroll
        for (int j = 0; j < 8; ++j) o[j] = (bf16)src[(size_t)j * D_];
        *(bf16x8*)(vtf_sw + (size_t)tile * 4096 + p * 8) = o;
    }
}

// ---------------- kv-split path: 4 WGs/CU (40 KB LDS), partial O + l out ----------------
__global__ __launch_bounds__(256, 4) void attn_split(const float* __restrict__ q,
                                                     const bf16* __restrict__ kbf_sw,
                                                     const bf16* __restrict__ vtf_sw,
                                                     bf16* __restrict__ pbuf,
                                                     float* __restrict__ lbuf) {
    __shared__ __align__(16) bf16 KV[2][2][4096];  // 32 KB: [buf][K/V][8KB tile]
    __shared__ __align__(16) bf16 Ps[4][1024];     // 8 KB: per-wave quarter-P band

    const int tid  = threadIdx.x;
    const int lane = tid & 63;
    const int wv   = tid >> 6;
    const int quad = lane >> 4;
    const int n16  = lane & 15;
    const int h7   = n16 & 7;

    const int bh = blockIdx.y;
    const int b  = bh >> 4;
    const int z  = blockIdx.z;            // kv half
    const int q0 = blockIdx.x * BM + wv * 64;

    const bf16* ktiles = kbf_sw + (size_t)b * 32 * 4096;
    const bf16* vtiles = vtf_sw + (size_t)b * 32 * 4096;

    // Q fragments (B-layout: k=d=quad*8+j, n=q=n16), pre-scaled
    bf16x8 qf[4][2];
    #pragma unroll
    for (int qt = 0; qt < 4; ++qt)
        #pragma unroll
        for (int ks = 0; ks < 2; ++ks) {
            const float* src = q + ((size_t)bh * N_ + q0 + qt * 16 + n16) * D_ + ks * 32 + quad * 8;
            float4 a = *(const float4*)src;
            float4 c = *(const float4*)(src + 4);
            bf16x8 pk;
            pk[0] = (bf16)(a.x * SCALE_LOG2E); pk[1] = (bf16)(a.y * SCALE_LOG2E);
            pk[2] = (bf16)(a.z * SCALE_LOG2E); pk[3] = (bf16)(a.w * SCALE_LOG2E);
            pk[4] = (bf16)(c.x * SCALE_LOG2E); pk[5] = (bf16)(c.y * SCALE_LOG2E);
            pk[6] = (bf16)(c.z * SCALE_LOG2E); pk[7] = (bf16)(c.w * SCALE_LOG2E);
            qf[qt][ks] = pk;
        }

    f32x4 acc[4][4];
    #pragma unroll
    for (int dt = 0; dt < 4; ++dt)
        #pragma unroll
        for (int qt = 0; qt < 4; ++qt) {
            acc[dt][qt][0] = 0.f; acc[dt][qt][1] = 0.f;
            acc[dt][qt][2] = 0.f; acc[dt][qt][3] = 0.f;
        }
    float lacc[4] = {0.f, 0.f, 0.f, 0.f};

    auto issue_dma = [&](int it, int p) {
        #pragma unroll
        for (int j = 0; j < 2; ++j) {
            const int c = wv * 2 + j;
            __builtin_amdgcn_global_load_lds(
                GBL(ktiles + (size_t)it * 4096 + c * 512 + lane * 8),
                LDS(&KV[p][0][c * 512]), 16, 0, 0);
            __builtin_amdgcn_global_load_lds(
                GBL(vtiles + (size_t)it * 4096 + c * 512 + lane * 8),
                LDS(&KV[p][1][c * 512]), 16, 0, 0);
        }
    };

    const int it0 = z * 16, it1 = it0 + 16;
    issue_dma(it0, 0);

    bf16* Pw = &Ps[wv][0];

    for (int it = it0; it < it1; ++it) {
        const int p = it & 1;
        __syncthreads();
        if (it + 1 < it1) issue_dma(it + 1, p ^ 1);

        bf16x8 kf[4][2], vf[2][4];
        #pragma unroll
        for (int kt = 0; kt < 4; ++kt)
            #pragma unroll
            for (int ks = 0; ks < 2; ++ks)
                kf[kt][ks] = *(const bf16x8*)&KV[p][0][(kt * 16 + n16) * 64 + ((4 * ks + quad) ^ h7) * 8];
        #pragma unroll
        for (int ks = 0; ks < 2; ++ks)
            #pragma unroll
            for (int dt = 0; dt < 4; ++dt)
                vf[ks][dt] = *(const bf16x8*)&KV[p][1][(dt * 16 + n16) * 64 + ((4 * ks + quad) ^ h7) * 8];

        #pragma unroll
        for (int qt = 0; qt < 4; ++qt) {
            f32x4 s[4];
            #pragma unroll
            for (int kt = 0; kt < 4; ++kt) {
                s[kt][0] = 0.f; s[kt][1] = 0.f; s[kt][2] = 0.f; s[kt][3] = 0.f;
            }
            #pragma unroll
            for (int kt = 0; kt < 4; ++kt) {
                s[kt] = __builtin_amdgcn_mfma_f32_16x16x32_bf16(kf[kt][0], qf[qt][0], s[kt], 0, 0, 0);
                s[kt] = __builtin_amdgcn_mfma_f32_16x16x32_bf16(kf[kt][1], qf[qt][1], s[kt], 0, 0, 0);
            }
            #pragma unroll
            for (int kt = 0; kt < 4; ++kt) {
                f32x4 pv;
                #pragma unroll
                for (int r = 0; r < 4; ++r) pv[r] = __builtin_amdgcn_exp2f(s[kt][r]);
                lacc[qt] += (pv[0] + pv[1]) + (pv[2] + pv[3]);
                bf16x4 pb;
                pb[0] = (bf16)pv[0]; pb[1] = (bf16)pv[1];
                pb[2] = (bf16)pv[2]; pb[3] = (bf16)pv[3];
                const int u = 2 * kt + (quad >> 1);
                *(bf16x4*)&Pw[n16 * 64 + ((u ^ h7) * 8) + (quad & 1) * 4] = pb;
            }
            // O^T(qt) += V^T P^T(qt)
            #pragma unroll
            for (int ks = 0; ks < 2; ++ks) {
                bf16x8 pb = *(const bf16x8*)&Pw[n16 * 64 + ((4 * ks + quad) ^ h7) * 8];
                #pragma unroll
                for (int dt = 0; dt < 4; ++dt)
                    acc[dt][qt] = __builtin_amdgcn_mfma_f32_16x16x32_bf16(vf[ks][dt], pb, acc[dt][qt], 0, 0, 0);
            }
        }
    }

    // epilogue: store unnormalized bf16 partial + l
    #pragma unroll
    for (int qt = 0; qt < 4; ++qt) {
        float l = lacc[qt];
        l += __shfl_xor(l, 16);
        l += __shfl_xor(l, 32);
        const int qrow = q0 + qt * 16 + n16;
        if (quad == 0)
            lbuf[((size_t)z * 64 + bh) * 2048 + qrow] = l;
        bf16* dst = pbuf + (((size_t)z * 64 + bh) * 2048 + qrow) * 64 + quad * 4;
        #pragma unroll
        for (int dt = 0; dt < 4; ++dt) {
            bf16x4 o;
            o[0] = (bf16)acc[dt][qt][0]; o[1] = (bf16)acc[dt][qt][1];
            o[2] = (bf16)acc[dt][qt][2]; o[3] = (bf16)acc[dt][qt][3];
            *(bf16x4*)(dst + dt * 16) = o;
        }
    }
}

// combine: out = (P0 + P1) / (l0 + l1)
__global__ __launch_bounds__(256) void combine(const bf16* __restrict__ pbuf,
                                               const float* __restrict__ lbuf,
                                               float* __restrict__ out) {
    const size_t t = (size_t)blockIdx.x * 256 + threadIdx.x;   // 1,048,576 threads
    const size_t e = t * 8;
    const size_t row = e >> 6;
    const float inv = 1.0f / (lbuf[row] + lbuf[131072 + row]);
    bf16x8 a = *(const bf16x8*)(pbuf + e);
    bf16x8 c = *(const bf16x8*)(pbuf + 8388608 + e);
    float4 o0, o1;
    o0.x = ((float)a[0] + (float)c[0]) * inv; o0.y = ((float)a[1] + (float)c[1]) * inv;
    o0.z = ((float)a[2] + (float)c[2]) * inv; o0.w = ((float)a[3] + (float)c[3]) * inv;
    o1.x = ((float)a[4] + (float)c[4]) * inv; o1.y = ((float)a[5] + (float)c[5]) * inv;
    o1.z = ((float)a[6] + (float)c[6]) * inv; o1.w = ((float)a[7] + (float)c[7]) * inv;
    *(float4*)(out + e)     = o0;
    *(float4*)(out + e + 4) = o1;
}

// ---------------- fallback path (R4 verbatim): used when ws too small ----------------
__global__ __launch_bounds__(256, 2) void attn_fwd(const float* __restrict__ q,
                                                   const bf16* __restrict__ kbf_sw,
                                                   const bf16* __restrict__ vtf_sw,
                                                   float* __restrict__ out) {
    __shared__ __align__(16) bf16 KV[2][2][4096];
    __shared__ __align__(16) bf16 Ps[4][4096];

    const int tid  = threadIdx.x;
    const int lane = tid & 63;
    const int wv   = tid >> 6;
    const int quad = lane >> 4;
    const int n16  = lane & 15;
    const int h7   = n16 & 7;

    const int bh = blockIdx.y;
    const int b  = bh >> 4;
    const int q0 = blockIdx.x * BM + wv * 64;

    const bf16* ktiles = kbf_sw + (size_t)b * 32 * 4096;
    const bf16* vtiles = vtf_sw + (size_t)b * 32 * 4096;

    bf16x8 qf[4][2];
    #pragma unroll
    for (int qt = 0; qt < 4; ++qt)
        #pragma unroll
        for (int ks = 0; ks < 2; ++ks) {
            const float* src = q + ((size_t)bh * N_ + q0 + qt * 16 + n16) * D_ + ks * 32 + quad * 8;
            float4 a = *(const float4*)src;
            float4 c = *(const float4*)(src + 4);
            bf16x8 pk;
            pk[0] = (bf16)(a.x * SCALE_LOG2E); pk[1] = (bf16)(a.y * SCALE_LOG2E);
            pk[2] = (bf16)(a.z * SCALE_LOG2E); pk[3] = (bf16)(a.w * SCALE_LOG2E);
            pk[4] = (bf16)(c.x * SCALE_LOG2E); pk[5] = (bf16)(c.y * SCALE_LOG2E);
            pk[6] = (bf16)(c.z * SCALE_LOG2E); pk[7] = (bf16)(c.w * SCALE_LOG2E);
            qf[qt][ks] = pk;
        }

    f32x4 acc[4][4];
    #pragma unroll
    for (int dt = 0; dt < 4; ++dt)
        #pragma unroll
        for (int qt = 0; qt < 4; ++qt) {
            acc[dt][qt][0] = 0.f; acc[dt][qt][1] = 0.f;
            acc[dt][qt][2] = 0.f; acc[dt][qt][3] = 0.f;
        }
    f32x4 lacc[4];
    #pragma unroll
    for (int qt = 0; qt < 4; ++qt) {
        lacc[qt][0] = 0.f; lacc[qt][1] = 0.f; lacc[qt][2] = 0.f; lacc[qt][3] = 0.f;
    }

    auto issue_dma = [&](int it, int p) {
        #pragma unroll
        for (int j = 0; j < 2; ++j) {
            const int c = wv * 2 + j;
            __builtin_amdgcn_global_load_lds(
                GBL(ktiles + (size_t)it * 4096 + c * 512 + lane * 8),
                LDS(&KV[p][0][c * 512]), 16, 0, 0);
            __builtin_amdgcn_global_load_lds(
                GBL(vtiles + (size_t)it * 4096 + c * 512 + lane * 8),
                LDS(&KV[p][1][c * 512]), 16, 0, 0);
        }
    };

    issue_dma(0, 0);
    bf16* Pw = &Ps[wv][0];

    for (int it = 0; it < N_ / BN; ++it) {
        const int p = it & 1;
        __syncthreads();
        if (it + 1 < N_ / BN) issue_dma(it + 1, p ^ 1);

        bf16x8 kf[4][2], vf[2][4];
        #pragma unroll
        for (int kt = 0; kt < 4; ++kt)
            #pragma unroll
            for (int ks = 0; ks < 2; ++ks)
                kf[kt][ks] = *(const bf16x8*)&KV[p][0][(kt * 16 + n16) * 64 + ((4 * ks + quad) ^ h7) * 8];
        #pragma unroll
        for (int ks = 0; ks < 2; ++ks)
            #pragma unroll
            for (int dt = 0; dt < 4; ++dt)
                vf[ks][dt] = *(const bf16x8*)&KV[p][1][(dt * 16 + n16) * 64 + ((4 * ks + quad) ^ h7) * 8];

        #pragma unroll
        for (int qt = 0; qt < 4; ++qt) {
            f32x4 s[4];
            #pragma unroll
            for (int kt = 0; kt < 4; ++kt) {
                s[kt][0] = 0.f; s[kt][1] = 0.f; s[kt][2] = 0.f; s[kt][3] = 0.f;
            }
            #pragma unroll
            for (int kt = 0; kt < 4; ++kt) {
                s[kt] = __builtin_amdgcn_mfma_f32_16x16x32_bf16(kf[kt][0], qf[qt][0], s[kt], 0, 0, 0);
                s[kt] = __builtin_amdgcn_mfma_f32_16x16x32_bf16(kf[kt][1], qf[qt][1], s[kt], 0, 0, 0);
            }
            #pragma unroll
            for (int kt = 0; kt < 4; ++kt) {
                f32x4 pv;
                #pragma unroll
                for (int r = 0; r < 4; ++r) pv[r] = __builtin_amdgcn_exp2f(s[kt][r]);
                lacc[qt] += pv;
                bf16x4 pb;
                pb[0] = (bf16)pv[0]; pb[1] = (bf16)pv[1];
                pb[2] = (bf16)pv[2]; pb[3] = (bf16)pv[3];
                const int u = 2 * kt + (quad >> 1);
                *(bf16x4*)&Pw[(qt * 16 + n16) * 64 + ((u ^ h7) * 8) + (quad & 1) * 4] = pb;
            }
        }

        #pragma unroll
        for (int ks = 0; ks < 2; ++ks)
            #pragma unroll
            for (int qt = 0; qt < 4; ++qt) {
                bf16x8 pb = *(const bf16x8*)&Pw[(qt * 16 + n16) * 64 + ((4 * ks + quad) ^ h7) * 8];
                #pragma unroll
                for (int dt = 0; dt < 4; ++dt)
                    acc[dt][qt] = __builtin_amdgcn_mfma_f32_16x16x32_bf16(vf[ks][dt], pb, acc[dt][qt], 0, 0, 0);
            }
    }

    #pragma unroll
    for (int qt = 0; qt < 4; ++qt) {
        float l = lacc[qt][0] + lacc[qt][1] + lacc[qt][2] + lacc[qt][3];
        l += __shfl_xor(l, 16);
        l += __shfl_xor(l, 32);
        float inv = 1.0f / l;
        const int qrow = q0 + qt * 16 + n16;
        float* dst = out + (size_t)(bh * N_ + qrow) * D_ + quad * 4;
        #pragma unroll
        for (int dt = 0; dt < 4; ++dt) {
            float4 o;
            o.x = acc[dt][qt][0] * inv; o.y = acc[dt][qt][1] * inv;
            o.z = acc[dt][qt][2] * inv; o.w = acc[dt][qt][3] * inv;
            *(float4*)(dst + dt * 16) = o;
        }
    }
}

extern "C" void kernel_launch(void* const* d_in, const int* in_sizes, int n_in,
                              void* d_out, int out_size, void* d_ws, size_t ws_size,
                              hipStream_t stream) {
    const float* q = (const float*)d_in[0];
    const float* k = (const float*)d_in[1];
    const float* v = (const float*)d_in[2];
    float* out = (float*)d_out;

    bf16*  kbf_sw = (bf16*)d_ws;                              // [0, 1 MB)
    bf16*  vtf_sw = kbf_sw + (size_t)B_ * N_ * D_;            // [1 MB, 2 MB)
    float* lbuf   = (float*)((char*)d_ws + (2u << 20));       // [2 MB, 3 MB)
    bf16*  pbuf   = (bf16*)((char*)d_ws + (4u << 20));        // [4 MB, 36 MB)

    convert_kv<<<B_ * 64, 256, 0, stream>>>(k, v, kbf_sw, vtf_sw);

    if (ws_size >= ((size_t)36 << 20)) {
        dim3 grid(N_ / BM, B_ * H_, 2);
        attn_split<<<grid, 256, 0, stream>>>(q, kbf_sw, vtf_sw, pbuf, lbuf);
        combine<<<4096, 256, 0, stream>>>(pbuf, lbuf, out);
    } else {
        dim3 grid(N_ / BM, B_ * H_);
        attn_fwd<<<grid, 256, 0, stream>>>(q, kbf_sw, vtf_sw, out);
    }
}

// Round 6
// 164.510 us; speedup vs baseline: 3.9238x; 3.9238x over previous
//
#include <hip/hip_runtime.h>
#include <hip/hip_bf16.h>

#define B_ 4
#define H_ 16
#define N_ 2048
#define D_ 64
#define BM 128   // q-rows per WG (32 per wave, 2 qt)
#define BN 64    // kv per iter

typedef __bf16 bf16;
typedef bf16 bf16x4 __attribute__((ext_vector_type(4)));
typedef bf16 bf16x8 __attribute__((ext_vector_type(8)));
typedef float f32x4 __attribute__((ext_vector_type(4)));

#define SCALE_LOG2E 0.18033688011112042f  // (1/sqrt(64)) * log2(e)

#define GBL(p) ((const __attribute__((address_space(1))) void*)(p))
#define LDS(p) ((__attribute__((address_space(3))) void*)(p))

// Build DMA-ready swizzled tile images in DRAM (512 blocks: tile x rep).
__global__ __launch_bounds__(256) void convert_kv(const float* __restrict__ k,
                                                  const float* __restrict__ v,
                                                  bf16* __restrict__ kbf_sw,
                                                  bf16* __restrict__ vtf_sw) {
    const int tile = blockIdx.x >> 1;
    const int rep  = blockIdx.x & 1;
    const int b = tile >> 5, T = tile & 31;
    const int t = threadIdx.x;

    const int p  = t + rep * 256;     // physical unit 0..511
    const int r  = p >> 3;            // row within tile
    const int up = p & 7;             // physical 16B unit
    const int u  = up ^ (r & 7);      // logical unit
    // K: row r = kv, unit u = d/8
    {
        const float* src = k + ((size_t)(b * N_ + T * 64 + r) * D_ + u * 8);
        float4 a = *(const float4*)src;
        float4 c = *(const float4*)(src + 4);
        bf16x8 o;
        o[0] = (bf16)a.x; o[1] = (bf16)a.y; o[2] = (bf16)a.z; o[3] = (bf16)a.w;
        o[4] = (bf16)c.x; o[5] = (bf16)c.y; o[6] = (bf16)c.z; o[7] = (bf16)c.w;
        *(bf16x8*)(kbf_sw + (size_t)tile * 4096 + p * 8) = o;
    }
    // V^T: row r = d, unit u = n_local/8 (transpose gathers, L1-amortized)
    {
        const float* src = v + ((size_t)(b * N_ + T * 64 + u * 8) * D_ + r);
        bf16x8 o;
        #pragma unroll
        for (int j = 0; j < 8; ++j) o[j] = (bf16)src[(size_t)j * D_];
        *(bf16x8*)(vtf_sw + (size_t)tile * 4096 + p * 8) = o;
    }
}

// Flash attention, S^T/O^T orientation. BM=128 (2 qt/wave), quarter-P bands:
// LDS = 32 KB KV dbuf + 8 KB P = 40 KB -> 4 WGs/CU (160 KB), grid 1024 = 4/CU
// = 4 waves/SIMD. Register budget <=128/wave (acc 32 AGPR) for full residency.
__global__ __launch_bounds__(256, 4) void attn_fwd(const float* __restrict__ q,
                                                   const bf16* __restrict__ kbf_sw,
                                                   const bf16* __restrict__ vtf_sw,
                                                   float* __restrict__ out) {
    __shared__ __align__(16) bf16 KV[2][2][4096];  // 32 KB: [buf][K/V][8KB tile]
    __shared__ __align__(16) bf16 Ps[4][1024];     // 8 KB: per-wave quarter-P band

    const int tid  = threadIdx.x;
    const int lane = tid & 63;
    const int wv   = tid >> 6;
    const int quad = lane >> 4;
    const int n16  = lane & 15;
    const int h7   = n16 & 7;

    const int bh = blockIdx.y;
    const int b  = bh >> 4;
    const int q0 = blockIdx.x * BM + wv * 32;

    const bf16* ktiles = kbf_sw + (size_t)b * 32 * 4096;
    const bf16* vtiles = vtf_sw + (size_t)b * 32 * 4096;

    // Q fragments (B-layout: k=d=quad*8+j, n=q=n16), pre-scaled
    bf16x8 qf[2][2];
    #pragma unroll
    for (int qt = 0; qt < 2; ++qt)
        #pragma unroll
        for (int ks = 0; ks < 2; ++ks) {
            const float* src = q + ((size_t)bh * N_ + q0 + qt * 16 + n16) * D_ + ks * 32 + quad * 8;
            float4 a = *(const float4*)src;
            float4 c = *(const float4*)(src + 4);
            bf16x8 pk;
            pk[0] = (bf16)(a.x * SCALE_LOG2E); pk[1] = (bf16)(a.y * SCALE_LOG2E);
            pk[2] = (bf16)(a.z * SCALE_LOG2E); pk[3] = (bf16)(a.w * SCALE_LOG2E);
            pk[4] = (bf16)(c.x * SCALE_LOG2E); pk[5] = (bf16)(c.y * SCALE_LOG2E);
            pk[6] = (bf16)(c.z * SCALE_LOG2E); pk[7] = (bf16)(c.w * SCALE_LOG2E);
            qf[qt][ks] = pk;
        }

    f32x4 acc[4][2];   // O^T frags [dt][qt]
    #pragma unroll
    for (int dt = 0; dt < 4; ++dt)
        #pragma unroll
        for (int qt = 0; qt < 2; ++qt) {
            acc[dt][qt][0] = 0.f; acc[dt][qt][1] = 0.f;
            acc[dt][qt][2] = 0.f; acc[dt][qt][3] = 0.f;
        }
    float lacc[2] = {0.f, 0.f};

    auto issue_dma = [&](int it, int p) {
        #pragma unroll
        for (int j = 0; j < 2; ++j) {
            const int c = wv * 2 + j;
            __builtin_amdgcn_global_load_lds(
                GBL(ktiles + (size_t)it * 4096 + c * 512 + lane * 8),
                LDS(&KV[p][0][c * 512]), 16, 0, 0);
            __builtin_amdgcn_global_load_lds(
                GBL(vtiles + (size_t)it * 4096 + c * 512 + lane * 8),
                LDS(&KV[p][1][c * 512]), 16, 0, 0);
        }
    };

    issue_dma(0, 0);
    bf16* Pw = &Ps[wv][0];

    for (int it = 0; it < N_ / BN; ++it) {
        const int p = it & 1;
        __syncthreads();                  // drains tile-it DMA; protects buf p^1
        if (it + 1 < N_ / BN) issue_dma(it + 1, p ^ 1);

        // K frags (A-layout: m=kv=n16, k=d) + V frags, swizzled b128 reads
        bf16x8 kf[4][2], vf[2][4];
        #pragma unroll
        for (int kt = 0; kt < 4; ++kt)
            #pragma unroll
            for (int ks = 0; ks < 2; ++ks)
                kf[kt][ks] = *(const bf16x8*)&KV[p][0][(kt * 16 + n16) * 64 + ((4 * ks + quad) ^ h7) * 8];
        #pragma unroll
        for (int ks = 0; ks < 2; ++ks)
            #pragma unroll
            for (int dt = 0; dt < 4; ++dt)
                vf[ks][dt] = *(const bf16x8*)&KV[p][1][(dt * 16 + n16) * 64 + ((4 * ks + quad) ^ h7) * 8];

        #pragma unroll
        for (int qt = 0; qt < 2; ++qt) {
            f32x4 s[4];
            #pragma unroll
            for (int kt = 0; kt < 4; ++kt) {
                s[kt][0] = 0.f; s[kt][1] = 0.f; s[kt][2] = 0.f; s[kt][3] = 0.f;
            }
            #pragma unroll
            for (int kt = 0; kt < 4; ++kt) {
                s[kt] = __builtin_amdgcn_mfma_f32_16x16x32_bf16(kf[kt][0], qf[qt][0], s[kt], 0, 0, 0);
                s[kt] = __builtin_amdgcn_mfma_f32_16x16x32_bf16(kf[kt][1], qf[qt][1], s[kt], 0, 0, 0);
            }
            #pragma unroll
            for (int kt = 0; kt < 4; ++kt) {
                f32x4 pv;
                #pragma unroll
                for (int r = 0; r < 4; ++r) pv[r] = __builtin_amdgcn_exp2f(s[kt][r]);
                lacc[qt] += (pv[0] + pv[1]) + (pv[2] + pv[3]);
                bf16x4 pb;
                pb[0] = (bf16)pv[0]; pb[1] = (bf16)pv[1];
                pb[2] = (bf16)pv[2]; pb[3] = (bf16)pv[3];
                const int u = 2 * kt + (quad >> 1);
                *(bf16x4*)&Pw[n16 * 64 + ((u ^ h7) * 8) + (quad & 1) * 4] = pb;
            }
            // O^T(qt) += V^T P^T(qt)  (wave-private band, no barrier)
            #pragma unroll
            for (int ks = 0; ks < 2; ++ks) {
                bf16x8 pb = *(const bf16x8*)&Pw[n16 * 64 + ((4 * ks + quad) ^ h7) * 8];
                #pragma unroll
                for (int dt = 0; dt < 4; ++dt)
                    acc[dt][qt] = __builtin_amdgcn_mfma_f32_16x16x32_bf16(vf[ks][dt], pb, acc[dt][qt], 0, 0, 0);
            }
        }
    }

    // epilogue: finish denominators (cross-quad), normalize, store float4
    #pragma unroll
    for (int qt = 0; qt < 2; ++qt) {
        float l = lacc[qt];
        l += __shfl_xor(l, 16);
        l += __shfl_xor(l, 32);
        float inv = 1.0f / l;
        const int qrow = q0 + qt * 16 + n16;
        float* dst = out + (size_t)(bh * N_ + qrow) * D_ + quad * 4;
        #pragma unroll
        for (int dt = 0; dt < 4; ++dt) {
            float4 o;
            o.x = acc[dt][qt][0] * inv; o.y = acc[dt][qt][1] * inv;
            o.z = acc[dt][qt][2] * inv; o.w = acc[dt][qt][3] * inv;
            *(float4*)(dst + dt * 16) = o;
        }
    }
}

extern "C" void kernel_launch(void* const* d_in, const int* in_sizes, int n_in,
                              void* d_out, int out_size, void* d_ws, size_t ws_size,
                              hipStream_t stream) {
    const float* q = (const float*)d_in[0];
    const float* k = (const float*)d_in[1];
    const float* v = (const float*)d_in[2];
    float* out = (float*)d_out;

    bf16* kbf_sw = (bf16*)d_ws;                        // [0, 1 MB)
    bf16* vtf_sw = kbf_sw + (size_t)B_ * N_ * D_;      // [1 MB, 2 MB)

    convert_kv<<<B_ * 64, 256, 0, stream>>>(k, v, kbf_sw, vtf_sw);
    dim3 grid(N_ / BM, B_ * H_);
    attn_fwd<<<grid, 256, 0, stream>>>(q, kbf_sw, vtf_sw, out);
}

// Round 7
// 155.318 us; speedup vs baseline: 4.1560x; 1.0592x over previous
//
#include <hip/hip_runtime.h>
#include <hip/hip_bf16.h>

#define B_ 4
#define H_ 16
#define N_ 2048
#define D_ 64
#define BM 256   // q-rows per WG (64 per wave)
#define BN 64    // kv per iter

typedef __bf16 bf16;
typedef bf16 bf16x4 __attribute__((ext_vector_type(4)));
typedef bf16 bf16x8 __attribute__((ext_vector_type(8)));
typedef float f32x2 __attribute__((ext_vector_type(2)));
typedef float f32x16 __attribute__((ext_vector_type(16)));

#define SCALE_LOG2E 0.18033688011112042f  // (1/sqrt(64)) * log2(e)

#define GBL(p) ((const __attribute__((address_space(1))) void*)(p))
#define LDS(p) ((__attribute__((address_space(3))) void*)(p))

// Per (b, kv-tile T of 64): 16 KB image in per-lane FRAGMENT ORDER for 32x32x16 MFMA.
//   K half  [0,8KB):  unit p=(mt*4+ks)*64+ln : A-frag K[kv=T*64+mt*32+(ln&31)][d=ks*16+(ln>>5)*8 ..+8]
//   V half  [8,16KB): unit p=(mt*4+ks)*64+ln : A-frag V^T[d=mt*32+(ln&31)][kv=T*64+ks*16+(ln>>5)*8 ..+8]
// -> LDS reads are lane-contiguous (conflict-free); DMA chunks are 1 KB coalesced.
__global__ __launch_bounds__(256) void convert_kv(const float* __restrict__ k,
                                                  const float* __restrict__ v,
                                                  bf16* __restrict__ img) {
    const int tile = blockIdx.x >> 1;             // b*32 + T
    const int b = tile >> 5, T = tile & 31;
    const int pu = (blockIdx.x & 1) * 256 + threadIdx.x;   // 0..511
    const int mtks = pu >> 6;
    const int ln   = pu & 63;
    const int mt = mtks >> 2, ks = mtks & 3;
    bf16* timg = img + (size_t)tile * 8192;       // 16 KB per tile

    // K unit
    {
        const int kvr = T * 64 + mt * 32 + (ln & 31);
        const int d0  = ks * 16 + (ln >> 5) * 8;
        const float* src = k + ((size_t)b * N_ + kvr) * D_ + d0;
        float4 a = *(const float4*)src;
        float4 c = *(const float4*)(src + 4);
        bf16x8 o;
        o[0] = (bf16)a.x; o[1] = (bf16)a.y; o[2] = (bf16)a.z; o[3] = (bf16)a.w;
        o[4] = (bf16)c.x; o[5] = (bf16)c.y; o[6] = (bf16)c.z; o[7] = (bf16)c.w;
        *(bf16x8*)(timg + pu * 8) = o;
    }
    // V unit (transpose gather, L1-amortized)
    {
        const int d   = mt * 32 + (ln & 31);
        const int kv0 = T * 64 + ks * 16 + (ln >> 5) * 8;
        const float* src = v + ((size_t)b * N_ + kv0) * D_ + d;
        bf16x8 o;
        #pragma unroll
        for (int j = 0; j < 8; ++j) o[j] = (bf16)src[(size_t)j * D_];
        *(bf16x8*)(timg + 4096 + pu * 8) = o;
    }
}

static __device__ inline bf16x4 pack4(float a, float b, float c, float d) {
    bf16x4 r; r[0] = (bf16)a; r[1] = (bf16)b; r[2] = (bf16)c; r[3] = (bf16)d; return r;
}
static __device__ inline bf16x4 xor32(bf16x4 x) {
    f32x2 f = __builtin_bit_cast(f32x2, x);
    f32x2 g;
    g[0] = __shfl_xor(f[0], 32);
    g[1] = __shfl_xor(f[1], 32);
    return __builtin_bit_cast(bf16x4, g);
}

// Flash attention on 32x32x16 MFMA, S^T/O^T orientation. P stays in registers:
// C-layout -> B-layout via one half-wave shfl_xor exchange per k-step.
__global__ __launch_bounds__(256, 2) void attn_fwd(const float* __restrict__ q,
                                                   const bf16* __restrict__ img,
                                                   float* __restrict__ out) {
    __shared__ __align__(16) bf16 KV[2][8192];    // double-buffered 16 KB tiles

    const int tid  = threadIdx.x;
    const int lane = tid & 63;
    const int wv   = tid >> 6;
    const int half = lane >> 5;
    const int l31  = lane & 31;

    const int bh = blockIdx.y;
    const int b  = bh >> 4;
    const int q0 = blockIdx.x * BM + wv * 64;

    const bf16* tiles = img + (size_t)b * 32 * 8192;

    // Q frags (B-layout for S^T: n=q=l31, k=d=ks*16+half*8+j), pre-scaled
    bf16x8 qf[2][4];
    #pragma unroll
    for (int qn = 0; qn < 2; ++qn)
        #pragma unroll
        for (int ks = 0; ks < 4; ++ks) {
            const float* src = q + ((size_t)bh * N_ + q0 + qn * 32 + l31) * D_ + ks * 16 + half * 8;
            float4 a = *(const float4*)src;
            float4 c = *(const float4*)(src + 4);
            bf16x8 pk;
            pk[0] = (bf16)(a.x * SCALE_LOG2E); pk[1] = (bf16)(a.y * SCALE_LOG2E);
            pk[2] = (bf16)(a.z * SCALE_LOG2E); pk[3] = (bf16)(a.w * SCALE_LOG2E);
            pk[4] = (bf16)(c.x * SCALE_LOG2E); pk[5] = (bf16)(c.y * SCALE_LOG2E);
            pk[6] = (bf16)(c.z * SCALE_LOG2E); pk[7] = (bf16)(c.w * SCALE_LOG2E);
            qf[qn][ks] = pk;
        }

    f32x16 acc[2][2] = {{{}, {}}, {{}, {}}};      // O^T tiles [mt_d][qn]
    float lacc[2] = {0.f, 0.f};

    auto issue_dma = [&](int it, int p) {
        const bf16* g = tiles + (size_t)it * 8192;
        #pragma unroll
        for (int j = 0; j < 4; ++j) {
            const int c = wv * 4 + j;             // 1 KB chunk 0..15
            __builtin_amdgcn_global_load_lds(GBL(g + c * 512 + lane * 8),
                                             LDS(&KV[p][c * 512]), 16, 0, 0);
        }
    };

    issue_dma(0, 0);

    for (int it = 0; it < N_ / BN; ++it) {
        const int p = it & 1;
        __syncthreads();                          // drains tile-it DMA; protects buf p^1
        if (it + 1 < N_ / BN) issue_dma(it + 1, p ^ 1);

        // A-frags, lane-contiguous (conflict-free b128)
        bf16x8 kf[2][4], vf[2][4];
        #pragma unroll
        for (int mt = 0; mt < 2; ++mt)
            #pragma unroll
            for (int ks = 0; ks < 4; ++ks) {
                kf[mt][ks] = *(const bf16x8*)&KV[p][((mt * 4 + ks) * 64 + lane) * 8];
                vf[mt][ks] = *(const bf16x8*)&KV[p][4096 + ((mt * 4 + ks) * 64 + lane) * 8];
            }

        #pragma unroll
        for (int qn = 0; qn < 2; ++qn) {
            // S^T = K Q^T : two 32x32 kv-tiles, C col=q=l31, row=kv
            f32x16 s[2] = {{}, {}};
            #pragma unroll
            for (int ks = 0; ks < 4; ++ks) {
                s[0] = __builtin_amdgcn_mfma_f32_32x32x16_bf16(kf[0][ks], qf[qn][ks], s[0], 0, 0, 0);
                s[1] = __builtin_amdgcn_mfma_f32_32x32x16_bf16(kf[1][ks], qf[qn][ks], s[1], 0, 0, 0);
            }
            #pragma unroll
            for (int mt = 0; mt < 2; ++mt) {
                float pv[16];
                #pragma unroll
                for (int r = 0; r < 16; ++r) pv[r] = __builtin_amdgcn_exp2f(s[mt][r]);
                float t0 = 0.f, t1 = 0.f;
                #pragma unroll
                for (int r = 0; r < 8; ++r) { t0 += pv[r]; t1 += pv[8 + r]; }
                lacc[qn] += t0 + t1;
                // C->B: per k-substep, half-wave exchange builds P^T B-frag in regs
                #pragma unroll
                for (int sp = 0; sp < 2; ++sp) {
                    bf16x4 lo  = pack4(pv[8 * sp + 0], pv[8 * sp + 1], pv[8 * sp + 2], pv[8 * sp + 3]);
                    bf16x4 hi  = pack4(pv[8 * sp + 4], pv[8 * sp + 5], pv[8 * sp + 6], pv[8 * sp + 7]);
                    bf16x4 xlo = xor32(lo), xhi = xor32(hi);
                    bf16x4 a0 = half ? xhi : lo;
                    bf16x4 a1 = half ? hi  : xlo;
                    bf16x8 bfrag = __builtin_shufflevector(a0, a1, 0, 1, 2, 3, 4, 5, 6, 7);
                    const int g = mt * 2 + sp;    // kv k-step 0..3
                    acc[0][qn] = __builtin_amdgcn_mfma_f32_32x32x16_bf16(vf[0][g], bfrag, acc[0][qn], 0, 0, 0);
                    acc[1][qn] = __builtin_amdgcn_mfma_f32_32x32x16_bf16(vf[1][g], bfrag, acc[1][qn], 0, 0, 0);
                }
            }
        }
    }

    // epilogue: denominator = own + partner half-wave partial; store float4
    #pragma unroll
    for (int qn = 0; qn < 2; ++qn) {
        float l = lacc[qn] + __shfl_xor(lacc[qn], 32);
        float inv = 1.0f / l;
        const int qrow = q0 + qn * 32 + l31;
        float* dst = out + ((size_t)bh * N_ + qrow) * D_ + 4 * half;
        #pragma unroll
        for (int mt = 0; mt < 2; ++mt)
            #pragma unroll
            for (int rq = 0; rq < 4; ++rq) {
                float4 o;
                o.x = acc[mt][qn][4 * rq + 0] * inv;
                o.y = acc[mt][qn][4 * rq + 1] * inv;
                o.z = acc[mt][qn][4 * rq + 2] * inv;
                o.w = acc[mt][qn][4 * rq + 3] * inv;
                *(float4*)(dst + mt * 32 + 8 * rq) = o;   // d = mt*32 + 8*rq + 4*half
            }
    }
}

extern "C" void kernel_launch(void* const* d_in, const int* in_sizes, int n_in,
                              void* d_out, int out_size, void* d_ws, size_t ws_size,
                              hipStream_t stream) {
    const float* q = (const float*)d_in[0];
    const float* k = (const float*)d_in[1];
    const float* v = (const float*)d_in[2];
    float* out = (float*)d_out;

    bf16* img = (bf16*)d_ws;                      // 128 tiles x 16 KB = 2 MB

    convert_kv<<<B_ * 64, 256, 0, stream>>>(k, v, img);
    dim3 grid(N_ / BM, B_ * H_);
    attn_fwd<<<grid, 256, 0, stream>>>(q, img, out);
}